// Round 5
// baseline (938.352 us; speedup 1.0000x reference)
//
#include <hip/hip_runtime.h>

#define NN 100000
#define NE 600000
#define DD 128
#define NL 4

typedef __attribute__((ext_vector_type(8))) short short8;
typedef __attribute__((ext_vector_type(4))) float float4v;

__device__ inline unsigned short f2bf(float f) {
  union { float f; unsigned u; } v; v.f = f;
  unsigned r = v.u + 0x7fff + ((v.u >> 16) & 1);  // round-to-nearest-even
  return (unsigned short)(r >> 16);
}
__device__ inline float bf2f(unsigned short u) {
  union { unsigned u; float f; } v; v.u = ((unsigned)u) << 16;
  return v.f;
}

// ---------------- utility ----------------
__global__ void k_zero_i(int* p, int n) {
  int i = blockIdx.x * 256 + threadIdx.x;
  if (i < n) p[i] = 0;
}
__global__ void k_zero_f(float* p, int n) {
  int i = blockIdx.x * 256 + threadIdx.x;
  if (i < n) p[i] = 0.f;
}
// fp32 [NN,128] -> bf16 mirror (for the gather payload)
__global__ void k_h2b(const float* __restrict__ src, unsigned short* __restrict__ dst) {
  int i = blockIdx.x * 256 + threadIdx.x;
  if (i >= NN * DD / 4) return;
  float4 v = ((const float4*)src)[i];
  ushort4 o;
  o.x = f2bf(v.x); o.y = f2bf(v.y); o.z = f2bf(v.z); o.w = f2bf(v.w);
  ((ushort4*)dst)[i] = o;
}

// ---------------- one-time: W1/W2 -> bf16, transposed [n][k] ----------------
__global__ void k_prep(const float* __restrict__ W1, const float* __restrict__ W2,
                       unsigned short* __restrict__ WT) {
  int i = blockIdx.x * 256 + threadIdx.x;  // over 8*16384
  if (i >= 8 * 16384) return;
  int m = i >> 14;
  int el = i & 16383;
  int k = el >> 7;
  int n = el & 127;
  const float* src = (m < 4) ? (W1 + (size_t)m * 16384) : (W2 + (size_t)(m - 4) * 16384);
  WT[(size_t)m * 16384 + n * 128 + k] = f2bf(src[k * 128 + n]);
}

// ---------------- CSR build (once per call) ----------------
__global__ void k_count(const int* __restrict__ ei, int* __restrict__ counts) {
  int e = blockIdx.x * 256 + threadIdx.x;
  if (e < NE) atomicAdd(&counts[ei[NE + e]], 1);
}

#define ST 256
#define SC 2
#define SB ((NN + ST * SC - 1) / (ST * SC))  // 196 blocks

__global__ void k_scan_part(const int* __restrict__ counts, int* __restrict__ row_ptr,
                            int* __restrict__ bsums) {
  __shared__ int s[ST];
  int b = blockIdx.x, t = threadIdx.x;
  int base = b * (ST * SC) + t * SC;
  int v0 = (base < NN) ? counts[base] : 0;
  int v1 = (base + 1 < NN) ? counts[base + 1] : 0;
  int tsum = v0 + v1;
  s[t] = tsum;
  __syncthreads();
  for (int d = 1; d < ST; d <<= 1) {
    int x = (t >= d) ? s[t - d] : 0;
    __syncthreads();
    s[t] += x;
    __syncthreads();
  }
  int excl = s[t] - tsum;
  if (base < NN) row_ptr[base] = excl;
  if (base + 1 < NN) row_ptr[base + 1] = excl + v0;
  if (t == ST - 1) bsums[b] = s[t];
}

__global__ void k_scan_bsum(const int* __restrict__ bsums, int* __restrict__ boffs,
                            int* __restrict__ row_ptr) {
  __shared__ int s[ST];
  int t = threadIdx.x;
  int v = (t < SB) ? bsums[t] : 0;
  s[t] = v;
  __syncthreads();
  for (int d = 1; d < ST; d <<= 1) {
    int x = (t >= d) ? s[t - d] : 0;
    __syncthreads();
    s[t] += x;
    __syncthreads();
  }
  if (t < SB) boffs[t] = s[t] - v;
  if (t == ST - 1) row_ptr[NN] = s[t];
}

__global__ void k_scan_add(const int* __restrict__ boffs, int* __restrict__ row_ptr,
                           int* __restrict__ off) {
  int b = blockIdx.x, t = threadIdx.x;
  int base = b * (ST * SC) + t * SC;
  int o = boffs[b];
  if (base < NN) { row_ptr[base] += o; off[base] = 0; }
  if (base + 1 < NN) { row_ptr[base + 1] += o; off[base + 1] = 0; }
}

__global__ void k_fill(const int* __restrict__ ei, const float* __restrict__ attr,
                       const int* __restrict__ row_ptr, int* __restrict__ off,
                       int* __restrict__ csr_src, float* __restrict__ csr_attr) {
  int e = blockIdx.x * 256 + threadIdx.x;
  if (e >= NE) return;
  int srcv = ei[e];
  int dstv = ei[NE + e];
  int pos = atomicAdd(&off[dstv], 1);
  int idx = row_ptr[dstv] + pos;
  csr_src[idx] = srcv;
  csr_attr[idx] = attr[e];
}

// ------- aggregation: z = (1+eps)*h + sum relu(hb[src]+attr*We+be), z fp32 out -------
// gather payload bf16 (256 B/row, halves gather traffic); self-term fp32
__global__ void k_agg(const float* __restrict__ h, const unsigned short* __restrict__ hb,
                      const int* __restrict__ row_ptr,
                      const int* __restrict__ csr_src, const float* __restrict__ csr_attr,
                      const float* __restrict__ We, const float* __restrict__ be,
                      const float* __restrict__ epsp, float* __restrict__ z) {
  int gid = blockIdx.x * blockDim.x + threadIdx.x;
  int n = gid >> 6;
  int lane = gid & 63;
  if (n >= NN) return;
  int d0 = lane * 2;
  float we0 = We[d0], we1 = We[d0 + 1];
  float be0 = be[d0], be1 = be[d0 + 1];
  float acc0 = 0.f, acc1 = 0.f;
  int b = row_ptr[n], e = row_ptr[n + 1];
  for (int i = b; i < e; i++) {
    int s = csr_src[i];
    float a = csr_attr[i];
    unsigned hv = *(const unsigned*)(hb + (size_t)s * DD + d0);
    float h0 = bf2f((unsigned short)(hv & 0xffffu));
    float h1 = bf2f((unsigned short)(hv >> 16));
    acc0 += fmaxf(h0 + fmaf(a, we0, be0), 0.f);
    acc1 += fmaxf(h1 + fmaf(a, we1, be1), 0.f);
  }
  float ep = 1.f + epsp[0];
  float2 hn = *(const float2*)(h + (size_t)n * DD + d0);
  float2 zv;
  zv.x = fmaf(ep, hn.x, acc0);
  zv.y = fmaf(ep, hn.y, acc1);
  *(float2*)(z + (size_t)n * DD + d0) = zv;
}

// ---------------- MFMA bf16 GEMM (R3-verified, verbatim) ----------------
// MODE 0: Y = X@W + b, fused column stats (sum, sumsq) -> stats[256]   (in-place X==Y safe)
// MODE 1: Y = relu( relu(X*scale+shift)@W + b )
// MODE 2: Y = hprev + relu( relu(X*scale+shift)@W + b )   (hprev==Y safe, disjoint rows)
template <int MODE>
__global__ __launch_bounds__(256) void k_gemm(
    const float* Xin, const unsigned short* __restrict__ WT,
    const float* __restrict__ bias, const float* __restrict__ bnp,
    const float* hprev, float* __restrict__ Yout, float* __restrict__ stats) {
  __shared__ unsigned short Wl[128 * 136];  // 34816 B
  __shared__ unsigned short Xl[64 * 136];   // 17408 B (aliased for stats reduce)
  const int tid = threadIdx.x;
  const int row0 = blockIdx.x * 64;

  // stage W^T bf16 [n][k] -> LDS (2048 x 16B, coalesced)
  for (int i = tid; i < 2048; i += 256) {
    int r = i >> 4, c = i & 15;
    *(uint4*)&Wl[r * 136 + c * 8] = *(const uint4*)&WT[r * 128 + c * 8];
  }
  // stage X rows: fp32 -> (BN+relu) -> bf16
  {
    int c4 = tid & 31;  // float4 column
    int rr = tid >> 5;
    float4 sc, sf;
    if (MODE >= 1) {
      sc = *(const float4*)(bnp + c4 * 4);
      sf = *(const float4*)(bnp + 128 + c4 * 4);
    }
    for (int it = 0; it < 8; it++) {
      int row = rr + it * 8;
      int gr = row0 + row;
      float4 v = make_float4(0.f, 0.f, 0.f, 0.f);
      if (gr < NN) {
        v = *(const float4*)(Xin + (size_t)gr * DD + c4 * 4);
        if (MODE >= 1) {
          v.x = fmaxf(fmaf(v.x, sc.x, sf.x), 0.f);
          v.y = fmaxf(fmaf(v.y, sc.y, sf.y), 0.f);
          v.z = fmaxf(fmaf(v.z, sc.z, sf.z), 0.f);
          v.w = fmaxf(fmaf(v.w, sc.w, sf.w), 0.f);
        }
      }
      ushort4 o;
      o.x = f2bf(v.x); o.y = f2bf(v.y); o.z = f2bf(v.z); o.w = f2bf(v.w);
      *(ushort4*)&Xl[row * 136 + c4 * 4] = o;
    }
  }
  __syncthreads();

  const int lane = tid & 63;
  const int w = tid >> 6;
  const int m = lane & 15;
  const int quad = lane >> 4;

  float4v acc[8];
#pragma unroll
  for (int ct = 0; ct < 8; ct++) {
    float b = bias[ct * 16 + m];
    acc[ct] = (float4v){b, b, b, b};
  }

  const unsigned short* Ap = &Xl[(w * 16 + m) * 136 + quad * 8];
  const unsigned short* Bp = &Wl[m * 136 + quad * 8];
#pragma unroll
  for (int q = 0; q < 4; q++) {
    short8 a = *(const short8*)(Ap + q * 32);
#pragma unroll
    for (int ct = 0; ct < 8; ct++) {
      short8 b = *(const short8*)(Bp + ct * 16 * 136 + q * 32);
      acc[ct] = __builtin_amdgcn_mfma_f32_16x16x32_bf16(a, b, acc[ct], 0, 0, 0);
    }
  }

  const int baserow = row0 + w * 16 + quad * 4;

  if (MODE == 0) {
    // fused BN column stats: sum & sumsq over valid rows
    __syncthreads();  // all waves done reading Xl; reuse as reduce scratch
    float* sarr = (float*)Xl;        // [4][128]
    float* sqarr = sarr + 512;       // [4][128]
#pragma unroll
    for (int ct = 0; ct < 8; ct++) {
      float s = 0.f, s2 = 0.f;
#pragma unroll
      for (int reg = 0; reg < 4; reg++) {
        float v = (baserow + reg < NN) ? acc[ct][reg] : 0.f;
        s += v;
        s2 = fmaf(v, v, s2);
      }
      s += __shfl_xor(s, 16); s += __shfl_xor(s, 32);
      s2 += __shfl_xor(s2, 16); s2 += __shfl_xor(s2, 32);
      if (quad == 0) {
        sarr[w * 128 + ct * 16 + m] = s;
        sqarr[w * 128 + ct * 16 + m] = s2;
      }
    }
    __syncthreads();
    if (tid < 128) {
      atomicAdd(&stats[tid], sarr[tid] + sarr[128 + tid] + sarr[256 + tid] + sarr[384 + tid]);
    } else {
      int c = tid - 128;
      atomicAdd(&stats[128 + c], sqarr[c] + sqarr[128 + c] + sqarr[256 + c] + sqarr[384 + c]);
    }
  }

  // epilogue stores
#pragma unroll
  for (int ct = 0; ct < 8; ct++) {
    int col = ct * 16 + m;
#pragma unroll
    for (int reg = 0; reg < 4; reg++) {
      int r = baserow + reg;
      if (r < NN) {
        float v = acc[ct][reg];
        if (MODE >= 1) v = fmaxf(v, 0.f);
        if (MODE == 2) v += hprev[(size_t)r * DD + col];
        Yout[(size_t)r * DD + col] = v;
      }
    }
  }
}

__global__ void k_bn_final(const float* __restrict__ stats, const float* __restrict__ gamma,
                           const float* __restrict__ beta, float* __restrict__ bnp) {
  int c = threadIdx.x;
  if (c >= 128) return;
  const float invN = 1.f / (float)NN;
  float mu = stats[c] * invN;
  float var = stats[128 + c] * invN - mu * mu;
  var = fmaxf(var, 0.f);
  float xx = var + 1e-5f;
  float r = rsqrtf(xx);
  r = r * (1.5f - 0.5f * xx * r * r);  // Newton step
  float scale = gamma[c] * r;
  bnp[c] = scale;
  bnp[128 + c] = beta[c] - mu * scale;
}

// ---------------- driver ----------------
static inline size_t align256(size_t x) { return (x + 255) & ~(size_t)255; }

extern "C" void kernel_launch(void* const* d_in, const int* in_sizes, int n_in,
                              void* d_out, int out_size, void* d_ws, size_t ws_size,
                              hipStream_t stream) {
  const float* x     = (const float*)d_in[0];
  const int*   ei    = (const int*)d_in[1];
  const float* attr  = (const float*)d_in[2];
  const float* We    = (const float*)d_in[3];
  const float* be    = (const float*)d_in[4];
  const float* eps   = (const float*)d_in[5];
  const float* W1    = (const float*)d_in[6];
  const float* b1    = (const float*)d_in[7];
  const float* gamma = (const float*)d_in[8];
  const float* beta  = (const float*)d_in[9];
  const float* W2    = (const float*)d_in[10];
  const float* b2    = (const float*)d_in[11];
  float* out = (float*)d_out;

  char* w = (char*)d_ws;
  float* z        = (float*)w; w += align256((size_t)NN * DD * 4);
  unsigned short* hb = (unsigned short*)w; w += align256((size_t)NN * DD * 2);
  int*   row_ptr  = (int*)w;   w += align256((size_t)(NN + 1) * 4);
  int*   counts   = (int*)w;   w += align256((size_t)NN * 4);
  int*   off      = (int*)w;   w += align256((size_t)NN * 4);
  int*   csr_src  = (int*)w;   w += align256((size_t)NE * 4);
  float* csr_attr = (float*)w; w += align256((size_t)NE * 4);
  float* stats    = (float*)w; w += align256(256 * 4);
  float* bnp      = (float*)w; w += align256(256 * 4);
  int*   bsums    = (int*)w;   w += align256(ST * 4);
  int*   boffs    = (int*)w;   w += align256(ST * 4);
  unsigned short* WTb = (unsigned short*)w; w += align256((size_t)8 * 16384 * 2);

  // weight prep + layer-0 bf16 mirror + CSR build
  k_prep<<<512, 256, 0, stream>>>(W1, W2, WTb);
  k_h2b<<<(NN * DD / 4 + 255) / 256, 256, 0, stream>>>(x, hb);
  k_zero_i<<<(NN + 255) / 256, 256, 0, stream>>>(counts, NN);
  k_count<<<(NE + 255) / 256, 256, 0, stream>>>(ei, counts);
  k_scan_part<<<SB, ST, 0, stream>>>(counts, row_ptr, bsums);
  k_scan_bsum<<<1, ST, 0, stream>>>(bsums, boffs, row_ptr);
  k_scan_add<<<SB, ST, 0, stream>>>(boffs, row_ptr, off);
  k_fill<<<(NE + 255) / 256, 256, 0, stream>>>(ei, attr, row_ptr, off, csr_src, csr_attr);

  const int NB = (NN + 63) / 64;  // 1563
  for (int l = 0; l < NL; l++) {
    const float* h = (l == 0) ? x : out;
    k_agg<<<(NN * 64 + 255) / 256, 256, 0, stream>>>(
        h, hb, row_ptr, csr_src, csr_attr, We + l * DD, be + l * DD, eps + l, z);
    k_zero_f<<<1, 256, 0, stream>>>(stats, 256);
    // z = z @ W1 + b1 (in-place), fused stats
    k_gemm<0><<<NB, 256, 0, stream>>>(z, WTb + (size_t)l * 16384, b1 + l * DD,
                                      nullptr, nullptr, z, stats);
    k_bn_final<<<1, 128, 0, stream>>>(stats, gamma + l * DD, beta + l * DD, bnp);
    if (l == 0)
      k_gemm<1><<<NB, 256, 0, stream>>>(z, WTb + (size_t)(4 + l) * 16384, b2 + l * DD,
                                        bnp, nullptr, out, nullptr);
    else
      k_gemm<2><<<NB, 256, 0, stream>>>(z, WTb + (size_t)(4 + l) * 16384, b2 + l * DD,
                                        bnp, out, out, nullptr);
    if (l < NL - 1)
      k_h2b<<<(NN * DD / 4 + 255) / 256, 256, 0, stream>>>(out, hb);
  }
}

// Round 6
// 779.387 us; speedup vs baseline: 1.2040x; 1.2040x over previous
//
#include <hip/hip_runtime.h>

#define NN 100000
#define NE 600000
#define DD 128
#define NL 4

typedef __attribute__((ext_vector_type(8))) short short8;
typedef __attribute__((ext_vector_type(4))) float float4v;

__device__ inline unsigned short f2bf(float f) {
  union { float f; unsigned u; } v; v.f = f;
  unsigned r = v.u + 0x7fff + ((v.u >> 16) & 1);  // round-to-nearest-even
  return (unsigned short)(r >> 16);
}
__device__ inline float bf2f(unsigned short u) {
  union { unsigned u; float f; } v; v.u = ((unsigned)u) << 16;
  return v.f;
}

// ---------------- utility ----------------
__global__ void k_zero_i(int* p, int n) {
  int i = blockIdx.x * 256 + threadIdx.x;
  if (i < n) p[i] = 0;
}
__global__ void k_zero_f(float* p, int n) {
  int i = blockIdx.x * 256 + threadIdx.x;
  if (i < n) p[i] = 0.f;
}
// fp32 [NN,128] -> bf16 mirror (layer-0 gather payload only; later layers fused in gemm2)
__global__ void k_h2b(const float* __restrict__ src, unsigned short* __restrict__ dst) {
  int i = blockIdx.x * 256 + threadIdx.x;
  if (i >= NN * DD / 4) return;
  float4 v = ((const float4*)src)[i];
  ushort4 o;
  o.x = f2bf(v.x); o.y = f2bf(v.y); o.z = f2bf(v.z); o.w = f2bf(v.w);
  ((ushort4*)dst)[i] = o;
}

// ---------------- one-time: W1/W2 -> bf16, transposed [n][k] ----------------
__global__ void k_prep(const float* __restrict__ W1, const float* __restrict__ W2,
                       unsigned short* __restrict__ WT) {
  int i = blockIdx.x * 256 + threadIdx.x;  // over 8*16384
  if (i >= 8 * 16384) return;
  int m = i >> 14;
  int el = i & 16383;
  int k = el >> 7;
  int n = el & 127;
  const float* src = (m < 4) ? (W1 + (size_t)m * 16384) : (W2 + (size_t)(m - 4) * 16384);
  WT[(size_t)m * 16384 + n * 128 + k] = f2bf(src[k * 128 + n]);
}

// ---------------- CSR build (once per call) ----------------
__global__ void k_count(const int* __restrict__ ei, int* __restrict__ counts) {
  int e = blockIdx.x * 256 + threadIdx.x;
  if (e < NE) atomicAdd(&counts[ei[NE + e]], 1);
}

#define ST 256
#define SC 2
#define SB ((NN + ST * SC - 1) / (ST * SC))  // 196 blocks

__global__ void k_scan_part(const int* __restrict__ counts, int* __restrict__ row_ptr,
                            int* __restrict__ bsums) {
  __shared__ int s[ST];
  int b = blockIdx.x, t = threadIdx.x;
  int base = b * (ST * SC) + t * SC;
  int v0 = (base < NN) ? counts[base] : 0;
  int v1 = (base + 1 < NN) ? counts[base + 1] : 0;
  int tsum = v0 + v1;
  s[t] = tsum;
  __syncthreads();
  for (int d = 1; d < ST; d <<= 1) {
    int x = (t >= d) ? s[t - d] : 0;
    __syncthreads();
    s[t] += x;
    __syncthreads();
  }
  int excl = s[t] - tsum;
  if (base < NN) row_ptr[base] = excl;
  if (base + 1 < NN) row_ptr[base + 1] = excl + v0;
  if (t == ST - 1) bsums[b] = s[t];
}

__global__ void k_scan_bsum(const int* __restrict__ bsums, int* __restrict__ boffs,
                            int* __restrict__ row_ptr) {
  __shared__ int s[ST];
  int t = threadIdx.x;
  int v = (t < SB) ? bsums[t] : 0;
  s[t] = v;
  __syncthreads();
  for (int d = 1; d < ST; d <<= 1) {
    int x = (t >= d) ? s[t - d] : 0;
    __syncthreads();
    s[t] += x;
    __syncthreads();
  }
  if (t < SB) boffs[t] = s[t] - v;
  if (t == ST - 1) row_ptr[NN] = s[t];
}

__global__ void k_scan_add(const int* __restrict__ boffs, int* __restrict__ row_ptr,
                           int* __restrict__ off) {
  int b = blockIdx.x, t = threadIdx.x;
  int base = b * (ST * SC) + t * SC;
  int o = boffs[b];
  if (base < NN) { row_ptr[base] += o; off[base] = 0; }
  if (base + 1 < NN) { row_ptr[base + 1] += o; off[base + 1] = 0; }
}

__global__ void k_fill(const int* __restrict__ ei, const float* __restrict__ attr,
                       const int* __restrict__ row_ptr, int* __restrict__ off,
                       int* __restrict__ csr_src, float* __restrict__ csr_attr) {
  int e = blockIdx.x * 256 + threadIdx.x;
  if (e >= NE) return;
  int srcv = ei[e];
  int dstv = ei[NE + e];
  int pos = atomicAdd(&off[dstv], 1);
  int idx = row_ptr[dstv] + pos;
  csr_src[idx] = srcv;
  csr_attr[idx] = attr[e];
}

// ------- aggregation: z = (1+eps)*h + sum relu(hb[src]+attr*We+be), z fp32 out -------
// ILP restructure: preload <=64 edge indices/attrs into per-lane regs (one coalesced
// load each), __shfl-broadcast in the loop, unroll x4 -> 4 independent gathers in flight.
__global__ void k_agg(const float* __restrict__ h, const unsigned short* __restrict__ hb,
                      const int* __restrict__ row_ptr,
                      const int* __restrict__ csr_src, const float* __restrict__ csr_attr,
                      const float* __restrict__ We, const float* __restrict__ be,
                      const float* __restrict__ epsp, float* __restrict__ z) {
  int gid = blockIdx.x * blockDim.x + threadIdx.x;
  int n = gid >> 6;
  int lane = gid & 63;
  if (n >= NN) return;
  int d0 = lane * 2;
  float we0 = We[d0], we1 = We[d0 + 1];
  float be0 = be[d0], be1 = be[d0 + 1];
  int b = row_ptr[n], e = row_ptr[n + 1];
  int deg = e - b;
  int cnt = (deg < 64) ? deg : 64;
  int myidx = (lane < cnt) ? csr_src[b + lane] : 0;
  float myatt = (lane < cnt) ? csr_attr[b + lane] : 0.f;
  float acc0 = 0.f, acc1 = 0.f;
  int i = 0;
  for (; i + 4 <= cnt; i += 4) {
    int s0 = __shfl(myidx, i);
    int s1 = __shfl(myidx, i + 1);
    int s2 = __shfl(myidx, i + 2);
    int s3 = __shfl(myidx, i + 3);
    float a0 = __shfl(myatt, i);
    float a1 = __shfl(myatt, i + 1);
    float a2 = __shfl(myatt, i + 2);
    float a3 = __shfl(myatt, i + 3);
    unsigned hv0 = *(const unsigned*)(hb + (size_t)s0 * DD + d0);
    unsigned hv1 = *(const unsigned*)(hb + (size_t)s1 * DD + d0);
    unsigned hv2 = *(const unsigned*)(hb + (size_t)s2 * DD + d0);
    unsigned hv3 = *(const unsigned*)(hb + (size_t)s3 * DD + d0);
    acc0 += fmaxf(bf2f((unsigned short)(hv0 & 0xffffu)) + fmaf(a0, we0, be0), 0.f);
    acc1 += fmaxf(bf2f((unsigned short)(hv0 >> 16)) + fmaf(a0, we1, be1), 0.f);
    acc0 += fmaxf(bf2f((unsigned short)(hv1 & 0xffffu)) + fmaf(a1, we0, be0), 0.f);
    acc1 += fmaxf(bf2f((unsigned short)(hv1 >> 16)) + fmaf(a1, we1, be1), 0.f);
    acc0 += fmaxf(bf2f((unsigned short)(hv2 & 0xffffu)) + fmaf(a2, we0, be0), 0.f);
    acc1 += fmaxf(bf2f((unsigned short)(hv2 >> 16)) + fmaf(a2, we1, be1), 0.f);
    acc0 += fmaxf(bf2f((unsigned short)(hv3 & 0xffffu)) + fmaf(a3, we0, be0), 0.f);
    acc1 += fmaxf(bf2f((unsigned short)(hv3 >> 16)) + fmaf(a3, we1, be1), 0.f);
  }
  for (; i < cnt; i++) {
    int s = __shfl(myidx, i);
    float a = __shfl(myatt, i);
    unsigned hv = *(const unsigned*)(hb + (size_t)s * DD + d0);
    acc0 += fmaxf(bf2f((unsigned short)(hv & 0xffffu)) + fmaf(a, we0, be0), 0.f);
    acc1 += fmaxf(bf2f((unsigned short)(hv >> 16)) + fmaf(a, we1, be1), 0.f);
  }
  // degree > 64 tail (essentially never with Poisson(6); correctness fallback)
  for (int j = b + 64; j < e; j++) {
    int s = csr_src[j];
    float a = csr_attr[j];
    unsigned hv = *(const unsigned*)(hb + (size_t)s * DD + d0);
    acc0 += fmaxf(bf2f((unsigned short)(hv & 0xffffu)) + fmaf(a, we0, be0), 0.f);
    acc1 += fmaxf(bf2f((unsigned short)(hv >> 16)) + fmaf(a, we1, be1), 0.f);
  }
  float ep = 1.f + epsp[0];
  float2 hn = *(const float2*)(h + (size_t)n * DD + d0);
  float2 zv;
  zv.x = fmaf(ep, hn.x, acc0);
  zv.y = fmaf(ep, hn.y, acc1);
  *(float2*)(z + (size_t)n * DD + d0) = zv;
}

// ---------------- MFMA bf16 GEMM (R3-verified; epilogue additionally mirrors to bf16) ------
// MODE 0: Y = X@W + b, fused column stats (sum, sumsq) -> stats[256]   (in-place X==Y safe)
// MODE 1: Y = relu( relu(X*scale+shift)@W + b );        hbout = bf16(Y) if non-null
// MODE 2: Y = hprev + relu( relu(X*scale+shift)@W + b );  same mirror   (hprev==Y safe)
template <int MODE>
__global__ __launch_bounds__(256) void k_gemm(
    const float* Xin, const unsigned short* __restrict__ WT,
    const float* __restrict__ bias, const float* __restrict__ bnp,
    const float* hprev, float* __restrict__ Yout, float* __restrict__ stats,
    unsigned short* __restrict__ hbout) {
  __shared__ unsigned short Wl[128 * 136];  // 34816 B
  __shared__ unsigned short Xl[64 * 136];   // 17408 B (aliased for stats reduce)
  const int tid = threadIdx.x;
  const int row0 = blockIdx.x * 64;

  // stage W^T bf16 [n][k] -> LDS (2048 x 16B, coalesced)
  for (int i = tid; i < 2048; i += 256) {
    int r = i >> 4, c = i & 15;
    *(uint4*)&Wl[r * 136 + c * 8] = *(const uint4*)&WT[r * 128 + c * 8];
  }
  // stage X rows: fp32 -> (BN+relu) -> bf16
  {
    int c4 = tid & 31;  // float4 column
    int rr = tid >> 5;
    float4 sc, sf;
    if (MODE >= 1) {
      sc = *(const float4*)(bnp + c4 * 4);
      sf = *(const float4*)(bnp + 128 + c4 * 4);
    }
    for (int it = 0; it < 8; it++) {
      int row = rr + it * 8;
      int gr = row0 + row;
      float4 v = make_float4(0.f, 0.f, 0.f, 0.f);
      if (gr < NN) {
        v = *(const float4*)(Xin + (size_t)gr * DD + c4 * 4);
        if (MODE >= 1) {
          v.x = fmaxf(fmaf(v.x, sc.x, sf.x), 0.f);
          v.y = fmaxf(fmaf(v.y, sc.y, sf.y), 0.f);
          v.z = fmaxf(fmaf(v.z, sc.z, sf.z), 0.f);
          v.w = fmaxf(fmaf(v.w, sc.w, sf.w), 0.f);
        }
      }
      ushort4 o;
      o.x = f2bf(v.x); o.y = f2bf(v.y); o.z = f2bf(v.z); o.w = f2bf(v.w);
      *(ushort4*)&Xl[row * 136 + c4 * 4] = o;
    }
  }
  __syncthreads();

  const int lane = tid & 63;
  const int w = tid >> 6;
  const int m = lane & 15;
  const int quad = lane >> 4;

  float4v acc[8];
#pragma unroll
  for (int ct = 0; ct < 8; ct++) {
    float b = bias[ct * 16 + m];
    acc[ct] = (float4v){b, b, b, b};
  }

  const unsigned short* Ap = &Xl[(w * 16 + m) * 136 + quad * 8];
  const unsigned short* Bp = &Wl[m * 136 + quad * 8];
#pragma unroll
  for (int q = 0; q < 4; q++) {
    short8 a = *(const short8*)(Ap + q * 32);
#pragma unroll
    for (int ct = 0; ct < 8; ct++) {
      short8 b = *(const short8*)(Bp + ct * 16 * 136 + q * 32);
      acc[ct] = __builtin_amdgcn_mfma_f32_16x16x32_bf16(a, b, acc[ct], 0, 0, 0);
    }
  }

  const int baserow = row0 + w * 16 + quad * 4;

  if (MODE == 0) {
    // fused BN column stats: sum & sumsq over valid rows
    __syncthreads();  // all waves done reading Xl; reuse as reduce scratch
    float* sarr = (float*)Xl;        // [4][128]
    float* sqarr = sarr + 512;       // [4][128]
#pragma unroll
    for (int ct = 0; ct < 8; ct++) {
      float s = 0.f, s2 = 0.f;
#pragma unroll
      for (int reg = 0; reg < 4; reg++) {
        float v = (baserow + reg < NN) ? acc[ct][reg] : 0.f;
        s += v;
        s2 = fmaf(v, v, s2);
      }
      s += __shfl_xor(s, 16); s += __shfl_xor(s, 32);
      s2 += __shfl_xor(s2, 16); s2 += __shfl_xor(s2, 32);
      if (quad == 0) {
        sarr[w * 128 + ct * 16 + m] = s;
        sqarr[w * 128 + ct * 16 + m] = s2;
      }
    }
    __syncthreads();
    if (tid < 128) {
      atomicAdd(&stats[tid], sarr[tid] + sarr[128 + tid] + sarr[256 + tid] + sarr[384 + tid]);
    } else {
      int c = tid - 128;
      atomicAdd(&stats[128 + c], sqarr[c] + sqarr[128 + c] + sqarr[256 + c] + sqarr[384 + c]);
    }
  }

  // epilogue stores
#pragma unroll
  for (int ct = 0; ct < 8; ct++) {
    int col = ct * 16 + m;
#pragma unroll
    for (int reg = 0; reg < 4; reg++) {
      int r = baserow + reg;
      if (r < NN) {
        float v = acc[ct][reg];
        if (MODE >= 1) v = fmaxf(v, 0.f);
        if (MODE == 2) v += hprev[(size_t)r * DD + col];
        Yout[(size_t)r * DD + col] = v;
        if (MODE >= 1 && hbout) hbout[(size_t)r * DD + col] = f2bf(v);
      }
    }
  }
}

__global__ void k_bn_final(const float* __restrict__ stats, const float* __restrict__ gamma,
                           const float* __restrict__ beta, float* __restrict__ bnp) {
  int c = threadIdx.x;
  if (c >= 128) return;
  const float invN = 1.f / (float)NN;
  float mu = stats[c] * invN;
  float var = stats[128 + c] * invN - mu * mu;
  var = fmaxf(var, 0.f);
  float xx = var + 1e-5f;
  float r = rsqrtf(xx);
  r = r * (1.5f - 0.5f * xx * r * r);  // Newton step
  float scale = gamma[c] * r;
  bnp[c] = scale;
  bnp[128 + c] = beta[c] - mu * scale;
}

// ---------------- driver ----------------
static inline size_t align256(size_t x) { return (x + 255) & ~(size_t)255; }

extern "C" void kernel_launch(void* const* d_in, const int* in_sizes, int n_in,
                              void* d_out, int out_size, void* d_ws, size_t ws_size,
                              hipStream_t stream) {
  const float* x     = (const float*)d_in[0];
  const int*   ei    = (const int*)d_in[1];
  const float* attr  = (const float*)d_in[2];
  const float* We    = (const float*)d_in[3];
  const float* be    = (const float*)d_in[4];
  const float* eps   = (const float*)d_in[5];
  const float* W1    = (const float*)d_in[6];
  const float* b1    = (const float*)d_in[7];
  const float* gamma = (const float*)d_in[8];
  const float* beta  = (const float*)d_in[9];
  const float* W2    = (const float*)d_in[10];
  const float* b2    = (const float*)d_in[11];
  float* out = (float*)d_out;

  char* w = (char*)d_ws;
  float* z        = (float*)w; w += align256((size_t)NN * DD * 4);
  unsigned short* hb = (unsigned short*)w; w += align256((size_t)NN * DD * 2);
  int*   row_ptr  = (int*)w;   w += align256((size_t)(NN + 1) * 4);
  int*   counts   = (int*)w;   w += align256((size_t)NN * 4);
  int*   off      = (int*)w;   w += align256((size_t)NN * 4);
  int*   csr_src  = (int*)w;   w += align256((size_t)NE * 4);
  float* csr_attr = (float*)w; w += align256((size_t)NE * 4);
  float* stats    = (float*)w; w += align256(256 * 4);
  float* bnp      = (float*)w; w += align256(256 * 4);
  int*   bsums    = (int*)w;   w += align256(ST * 4);
  int*   boffs    = (int*)w;   w += align256(ST * 4);
  unsigned short* WTb = (unsigned short*)w; w += align256((size_t)8 * 16384 * 2);

  // weight prep + layer-0 bf16 mirror + CSR build
  k_prep<<<512, 256, 0, stream>>>(W1, W2, WTb);
  k_h2b<<<(NN * DD / 4 + 255) / 256, 256, 0, stream>>>(x, hb);
  k_zero_i<<<(NN + 255) / 256, 256, 0, stream>>>(counts, NN);
  k_count<<<(NE + 255) / 256, 256, 0, stream>>>(ei, counts);
  k_scan_part<<<SB, ST, 0, stream>>>(counts, row_ptr, bsums);
  k_scan_bsum<<<1, ST, 0, stream>>>(bsums, boffs, row_ptr);
  k_scan_add<<<SB, ST, 0, stream>>>(boffs, row_ptr, off);
  k_fill<<<(NE + 255) / 256, 256, 0, stream>>>(ei, attr, row_ptr, off, csr_src, csr_attr);

  const int NB = (NN + 63) / 64;  // 1563
  for (int l = 0; l < NL; l++) {
    const float* h = (l == 0) ? x : out;
    k_agg<<<(NN * 64 + 255) / 256, 256, 0, stream>>>(
        h, hb, row_ptr, csr_src, csr_attr, We + l * DD, be + l * DD, eps + l, z);
    k_zero_f<<<1, 256, 0, stream>>>(stats, 256);
    // z = z @ W1 + b1 (in-place), fused stats
    k_gemm<0><<<NB, 256, 0, stream>>>(z, WTb + (size_t)l * 16384, b1 + l * DD,
                                      nullptr, nullptr, z, stats, nullptr);
    k_bn_final<<<1, 128, 0, stream>>>(stats, gamma + l * DD, beta + l * DD, bnp);
    unsigned short* hbo = (l < NL - 1) ? hb : nullptr;
    if (l == 0)
      k_gemm<1><<<NB, 256, 0, stream>>>(z, WTb + (size_t)(4 + l) * 16384, b2 + l * DD,
                                        bnp, nullptr, out, nullptr, hbo);
    else
      k_gemm<2><<<NB, 256, 0, stream>>>(z, WTb + (size_t)(4 + l) * 16384, b2 + l * DD,
                                        bnp, out, out, nullptr, hbo);
  }
}